// Round 7
// baseline (62.700 us; speedup 1.0000x reference)
//
#include <hip/hip_runtime.h>
#include <math.h>

// PROBE ROUND: round-6 kernel logic, repeated 8x in-kernel (idempotent; CSE
// defeated via asm opaque on bin origin) so the dispatch exceeds the harness
// fill kernels (~40us) and shows up in rocprof top-5 WITH counters.
//   diagnosis: (dur-3.8)/8 = per-rep body; VALUBusy / Occupancy / FETCH
//   disambiguate VALU-bound vs latency-bound vs cold-cache-bound.
//
// RoI pooling: fm [2,56,56,256] f32, rois [2,48,4] f32 (x, y_max, w, h),
// out [2,48,7,7,256] f32. One WAVE per bin; lane = 4 channels as float4.
// Clamped compile-time 4x4 chunks, one vmcnt wait per 16 loads.

#define NB 2
#define NR 48
#define FH 56
#define FW 56
#define PH 7
#define PW 7
#define NBINS (NB * NR * PH * PW)   // 4704 = 1176 blocks * 4 waves exactly
#define REPS 8

__device__ inline void fm4max(float4& m, const float4 v) {
  m.x = fmaxf(m.x, v.x);
  m.y = fmaxf(m.y, v.y);
  m.z = fmaxf(m.z, v.z);
  m.w = fmaxf(m.w, v.w);
}

// Pool rows [r0, r0+Eh) x cols [c0, c0+Ew) in clamped CHxCW chunks.
template <int CH, int CW>
__device__ inline float4 pool_bin(const float4* __restrict__ base,
                                  int r0, int Eh, int c0, int Ew) {
  float4 m0 = make_float4(-INFINITY, -INFINITY, -INFINITY, -INFINITY);
  float4 m1 = m0;
  for (int rc = 0; rc < Eh; rc += CH) {
    for (int cc = 0; cc < Ew; cc += CW) {
      float4 v[CH][CW];
#pragma unroll
      for (int k = 0; k < CH; ++k) {
        int rr = rc + k;
        rr = (rr < Eh) ? rr : (Eh - 1);       // clamp: re-read last row
        const float4* rowp = base + (size_t)((r0 + rr) * FW) * 64;
#pragma unroll
        for (int q = 0; q < CW; ++q) {
          int c = cc + q;
          c = (c < Ew) ? c : (Ew - 1);        // clamp: re-read last col
          v[k][q] = rowp[(size_t)(c0 + c) * 64];
        }
      }
#pragma unroll
      for (int k = 0; k < CH; ++k) {
#pragma unroll
        for (int q = 0; q < CW; ++q) {
          if (((k * CW + q) & 1) == 0) fm4max(m0, v[k][q]);
          else                         fm4max(m1, v[k][q]);
        }
      }
    }
  }
  fm4max(m0, m1);
  return m0;
}

__global__ __launch_bounds__(256) void roi_pool_kernel(
    const float4* __restrict__ fm4, const float* __restrict__ rois,
    float4* __restrict__ out4) {
  const int lane = threadIdx.x & 63;          // channel group (4 ch each)
  int bin = __builtin_amdgcn_readfirstlane(blockIdx.x * 4 + (threadIdx.x >> 6));
  const int obin = bin;

  const int j = bin % PW; bin /= PW;
  const int i = bin % PH; bin /= PH;
  const int r = bin % NR;
  const int b = bin / NR;

  const float* roi = rois + (b * NR + r) * 4;
  const float x = roi[0], y = roi[1], w = roi[2], h = roi[3];

  // Match JAX reference fp32 arithmetic + trunc-to-int32 exactly.
  const int w_start = (int)(56.0f * x);
  const int w_end   = (int)(56.0f * (x + w));
  const int h_start = (int)(56.0f * (1.0f - y));
  const int h_end   = (int)(56.0f * (1.0f - y + h));
  const int rh = h_end - h_start;
  const int rw = w_end - w_start;
  const int h_step = rh / PH;
  const int w_step = rw / PW;

  const int r0 = h_start + i * h_step;
  const int r1 = (i == PH - 1) ? (h_start + rh) : (r0 + h_step);
  const int c0 = w_start + j * w_step;
  const int c1 = (j == PW - 1) ? (w_start + rw) : (c0 + w_step);

  const int Eh = r1 - r0;                     // in [2, 10]
  const int Ew = c1 - c0;                     // in [2, 10]

  const float4* fmbase = fm4 + ((size_t)(b * FH) * FW) * 64 + lane;

  for (int rep = 0; rep < REPS; ++rep) {
    int r0v = r0, c0v = c0;
    // Opaque: compiler can't prove reps identical -> all 8 bodies stay live.
    asm volatile("" : "+v"(r0v), "+v"(c0v));
    const float4 m = pool_bin<4, 4>(fmbase, r0v, Eh, c0v, Ew);
    out4[(size_t)obin * 64 + lane] = m;
  }
}

extern "C" void kernel_launch(void* const* d_in, const int* in_sizes, int n_in,
                              void* d_out, int out_size, void* d_ws, size_t ws_size,
                              hipStream_t stream) {
  const float4* fm4 = (const float4*)d_in[0];
  const float* rois = (const float*)d_in[1];
  float4* out4 = (float4*)d_out;
  roi_pool_kernel<<<NBINS / 4, 256, 0, stream>>>(fm4, rois, out4);
}

// Round 8
// 12.685 us; speedup vs baseline: 4.9429x; 4.9429x over previous
//
#include <hip/hip_runtime.h>
#include <math.h>

// RoI pooling: fm [2,56,56,256] f32, rois [2,48,4] f32 (x, y_max, w, h),
// out [2,48,7,7,256] f32.
//
// One WAVE (= one 64-thread block) per output bin; lane l holds channels
// 4l..4l+3 as a float4 (1 KB/wave coalesced loads). Geometry is wave-uniform
// (blockIdx) -> SALU.
//
// Round-7 probe showed VGPR=36: the compiler serialized the "batched" chunk
// loads into load->wait->fmax chains (~280cy each; avg wave 2.45us/rep).
// This round forces the batch: 16 global_load_dwordx4 via inline asm with
// distinct "=v" outputs (16 outstanding), ONE s_waitcnt vmcnt(0), then
// sched_barrier(0) so the fmax consumers can't hoist past the wait (rule
// #18), then the fmax tree. Worst 10x10 bin: 9 waits; common bins: 1.

#define NB 2
#define NR 48
#define FH 56
#define FW 56
#define PH 7
#define PW 7
#define NBINS (NB * NR * PH * PW)   // 4704 blocks, 1 wave each

__device__ inline void fm4max(float4& m, const float4 v) {
  m.x = fmaxf(m.x, v.x);
  m.y = fmaxf(m.y, v.y);
  m.z = fmaxf(m.z, v.z);
  m.w = fmaxf(m.w, v.w);
}

__device__ inline float4 gload(const float4* p) {
  float4 v;
  asm volatile("global_load_dwordx4 %0, %1, off" : "=v"(v) : "v"(p));
  return v;
}

__global__ __launch_bounds__(64) void roi_pool_kernel(
    const float4* __restrict__ fm4, const float* __restrict__ rois,
    float4* __restrict__ out4) {
  const int lane = threadIdx.x;               // channel group (4 ch each)
  int bin = blockIdx.x;                       // wave-uniform
  const int obin = bin;

  const int j = bin % PW; bin /= PW;
  const int i = bin % PH; bin /= PH;
  const int r = bin % NR;
  const int b = bin / NR;

  const float* roi = rois + (b * NR + r) * 4;
  const float x = roi[0], y = roi[1], w = roi[2], h = roi[3];

  // Match JAX reference fp32 arithmetic + trunc-to-int32 exactly.
  const int w_start = (int)(56.0f * x);
  const int w_end   = (int)(56.0f * (x + w));
  const int h_start = (int)(56.0f * (1.0f - y));
  const int h_end   = (int)(56.0f * (1.0f - y + h));
  const int rh = h_end - h_start;
  const int rw = w_end - w_start;
  const int h_step = rh / PH;
  const int w_step = rw / PW;

  const int r0 = h_start + i * h_step;
  const int r1 = (i == PH - 1) ? (h_start + rh) : (r0 + h_step);
  const int c0 = w_start + j * w_step;
  const int c1 = (j == PW - 1) ? (w_start + rw) : (c0 + w_step);

  const int Eh = r1 - r0;                     // in [2, 10]
  const int Ew = c1 - c0;                     // in [2, 10]

  const float4* base = fm4 + ((size_t)(b * FH) * FW) * 64 + lane;

  float4 m0 = make_float4(-INFINITY, -INFINITY, -INFINITY, -INFINITY);
  float4 m1 = m0, m2 = m0, m3 = m0;

  // Clamped compile-time 4x4 chunks; duplicate reads harmless under max.
  for (int rc = 0; rc < Eh; rc += 4) {
    for (int cc = 0; cc < Ew; cc += 4) {
      float4 v[16];
#pragma unroll
      for (int k = 0; k < 4; ++k) {
        int rr = rc + k;
        rr = (rr < Eh) ? rr : (Eh - 1);       // clamp: re-read last row
        const float4* rowp = base + (size_t)((r0 + rr) * FW) * 64;
#pragma unroll
        for (int q = 0; q < 4; ++q) {
          int c = cc + q;
          c = (c < Ew) ? c : (Ew - 1);        // clamp: re-read last col
          v[k * 4 + q] = gload(rowp + (size_t)(c0 + c) * 64);
        }
      }
      // One wait for all 16 outstanding loads; fence consumer hoisting.
      asm volatile("s_waitcnt vmcnt(0)" ::: "memory");
      __builtin_amdgcn_sched_barrier(0);
#pragma unroll
      for (int k = 0; k < 4; ++k) {
        fm4max(m0, v[k * 4 + 0]);
        fm4max(m1, v[k * 4 + 1]);
        fm4max(m2, v[k * 4 + 2]);
        fm4max(m3, v[k * 4 + 3]);
      }
    }
  }
  fm4max(m0, m1);
  fm4max(m2, m3);
  fm4max(m0, m2);

  out4[(size_t)obin * 64 + lane] = m0;
}

extern "C" void kernel_launch(void* const* d_in, const int* in_sizes, int n_in,
                              void* d_out, int out_size, void* d_ws, size_t ws_size,
                              hipStream_t stream) {
  const float4* fm4 = (const float4*)d_in[0];
  const float* rois = (const float*)d_in[1];
  float4* out4 = (float4*)d_out;
  roi_pool_kernel<<<NBINS, 64, 0, stream>>>(fm4, rois, out4);
}

// Round 9
// 11.850 us; speedup vs baseline: 5.2910x; 1.0704x over previous
//
#include <hip/hip_runtime.h>
#include <math.h>

// RoI pooling: fm [2,56,56,256] f32, rois [2,48,4] f32 (x, y_max, w, h),
// out [2,48,7,7,256] f32.
//
// One WAVE (= one 64-thread block) per output bin; lane l = channels
// 4l..4l+3 as float4 (1 KB/wave coalesced loads). Geometry wave-uniform.
//
// Round 9 changes:
//  (a) EXACT-extent load batches. Extents (Eh,Ew) in [2,10]^2, and 73% of
//      bins have both <=4: wave-uniform switch to pool_exact<EH,EW> -- all
//      EH*EW loads issued via inline-asm (compiler can't serialize; round-7
//      probe showed VGPR=36 serialization), ONE s_waitcnt vmcnt(0) +
//      sched_barrier(0) (rule #18). Edge/corner bins: clamped chunk loops,
//      <=16 loads per batch. Cuts L2 traffic ~1.7x vs clamp-to-4x4.
//  (b) XCD swizzle: phys block p -> logical bin L=(p&7)*588+(p>>3); with
//      round-robin p%8->XCD placement, image b=0 maps to XCDs 0-3, b=1 to
//      4-7: per-XCD working set 3.2 MB fits the 4 MB L2 (no thrash), and a
//      ROI's 49 bins stay on one XCD.

#define NB 2
#define NR 48
#define FH 56
#define FW 56
#define PH 7
#define PW 7
#define NBINS (NB * NR * PH * PW)   // 4704 = 8 XCD groups * 588

__device__ inline void fm4max(float4& m, const float4 v) {
  m.x = fmaxf(m.x, v.x);
  m.y = fmaxf(m.y, v.y);
  m.z = fmaxf(m.z, v.z);
  m.w = fmaxf(m.w, v.w);
}

__device__ inline float4 gload(const float4* p) {
  float4 v;
  asm volatile("global_load_dwordx4 %0, %1, off" : "=v"(v) : "v"(p));
  return v;
}

// Exactly EHxEW pixels, no padding: one batch, one wait.
template <int EH, int EW>
__device__ inline float4 pool_exact(const float4* __restrict__ base,
                                    int r0, int c0) {
  float4 v[EH][EW];
#pragma unroll
  for (int k = 0; k < EH; ++k) {
    const float4* rowp = base + (size_t)((r0 + k) * FW) * 64;
#pragma unroll
    for (int q = 0; q < EW; ++q) v[k][q] = gload(rowp + (size_t)(c0 + q) * 64);
  }
  asm volatile("s_waitcnt vmcnt(0)" ::: "memory");
  __builtin_amdgcn_sched_barrier(0);
  float4 m0 = v[0][0], m1 = v[0][1];   // EW >= 2 always
  float4 m2 = v[1][0], m3 = v[1][1];   // EH >= 2 always
#pragma unroll
  for (int k = 0; k < EH; ++k)
#pragma unroll
    for (int q = 0; q < EW; ++q) {
      if (k < 2 && q < 2) continue;
      const int s = (k * EW + q) & 3;
      if (s == 0) fm4max(m0, v[k][q]);
      else if (s == 1) fm4max(m1, v[k][q]);
      else if (s == 2) fm4max(m2, v[k][q]);
      else fm4max(m3, v[k][q]);
    }
  fm4max(m0, m1); fm4max(m2, m3); fm4max(m0, m2);
  return m0;
}

// Clamped CHxCW chunk loop for extents > 4 (duplicates harmless under max).
template <int CH, int CW>
__device__ inline float4 pool_loop(const float4* __restrict__ base,
                                   int r0, int Eh, int c0, int Ew) {
  float4 m0 = make_float4(-INFINITY, -INFINITY, -INFINITY, -INFINITY);
  float4 m1 = m0, m2 = m0, m3 = m0;
  for (int rc = 0; rc < Eh; rc += CH) {
    for (int cc = 0; cc < Ew; cc += CW) {
      float4 v[CH][CW];
#pragma unroll
      for (int k = 0; k < CH; ++k) {
        int rr = rc + k; rr = (rr < Eh) ? rr : (Eh - 1);
        const float4* rowp = base + (size_t)((r0 + rr) * FW) * 64;
#pragma unroll
        for (int q = 0; q < CW; ++q) {
          int c = cc + q; c = (c < Ew) ? c : (Ew - 1);
          v[k][q] = gload(rowp + (size_t)(c0 + c) * 64);
        }
      }
      asm volatile("s_waitcnt vmcnt(0)" ::: "memory");
      __builtin_amdgcn_sched_barrier(0);
#pragma unroll
      for (int k = 0; k < CH; ++k)
#pragma unroll
        for (int q = 0; q < CW; ++q) {
          const int s = (k * CW + q) & 3;
          if (s == 0) fm4max(m0, v[k][q]);
          else if (s == 1) fm4max(m1, v[k][q]);
          else if (s == 2) fm4max(m2, v[k][q]);
          else fm4max(m3, v[k][q]);
        }
    }
  }
  fm4max(m0, m1); fm4max(m2, m3); fm4max(m0, m2);
  return m0;
}

__global__ __launch_bounds__(64) void roi_pool_kernel(
    const float4* __restrict__ fm4, const float* __restrict__ rois,
    float4* __restrict__ out4) {
  const int lane = threadIdx.x;               // channel group (4 ch each)
  // XCD swizzle: round-robin p%8 -> XCD; give each XCD a contiguous 588-bin
  // slab. b=0 bins (L<2352) land on XCDs 0-3, b=1 on 4-7.
  const int p = blockIdx.x;
  int bin = (p & 7) * (NBINS / 8) + (p >> 3);
  const int obin = bin;

  const int j = bin % PW; bin /= PW;
  const int i = bin % PH; bin /= PH;
  const int r = bin % NR;
  const int b = bin / NR;

  const float* roi = rois + (b * NR + r) * 4;
  const float x = roi[0], y = roi[1], w = roi[2], h = roi[3];

  // Match JAX reference fp32 arithmetic + trunc-to-int32 exactly.
  const int w_start = (int)(56.0f * x);
  const int w_end   = (int)(56.0f * (x + w));
  const int h_start = (int)(56.0f * (1.0f - y));
  const int h_end   = (int)(56.0f * (1.0f - y + h));
  const int rh = h_end - h_start;
  const int rw = w_end - w_start;
  const int h_step = rh / PH;
  const int w_step = rw / PW;

  const int r0 = h_start + i * h_step;
  const int r1 = (i == PH - 1) ? (h_start + rh) : (r0 + h_step);
  const int c0 = w_start + j * w_step;
  const int c1 = (j == PW - 1) ? (w_start + rw) : (c0 + w_step);

  const int Eh = r1 - r0;                     // in [2, 10]
  const int Ew = c1 - c0;                     // in [2, 10]

  const float4* base = fm4 + ((size_t)(b * FH) * FW) * 64 + lane;

  float4 m;
  if (Eh <= 4 && Ew <= 4) {                   // ~73% of bins: exact, 1 wait
    switch ((Eh - 2) * 3 + (Ew - 2)) {
      case 0: m = pool_exact<2, 2>(base, r0, c0); break;
      case 1: m = pool_exact<2, 3>(base, r0, c0); break;
      case 2: m = pool_exact<2, 4>(base, r0, c0); break;
      case 3: m = pool_exact<3, 2>(base, r0, c0); break;
      case 4: m = pool_exact<3, 3>(base, r0, c0); break;
      case 5: m = pool_exact<3, 4>(base, r0, c0); break;
      case 6: m = pool_exact<4, 2>(base, r0, c0); break;
      case 7: m = pool_exact<4, 3>(base, r0, c0); break;
      default: m = pool_exact<4, 4>(base, r0, c0); break;
    }
  } else if (Eh <= 4) {                       // wide last-col bins
    switch (Eh) {
      case 2: m = pool_loop<2, 4>(base, r0, Eh, c0, Ew); break;
      case 3: m = pool_loop<3, 4>(base, r0, Eh, c0, Ew); break;
      default: m = pool_loop<4, 4>(base, r0, Eh, c0, Ew); break;
    }
  } else if (Ew <= 4) {                       // tall last-row bins
    switch (Ew) {
      case 2: m = pool_loop<4, 2>(base, r0, Eh, c0, Ew); break;
      case 3: m = pool_loop<4, 3>(base, r0, Eh, c0, Ew); break;
      default: m = pool_loop<4, 4>(base, r0, Eh, c0, Ew); break;
    }
  } else {                                    // ~2%: corner bins
    m = pool_loop<4, 4>(base, r0, Eh, c0, Ew);
  }

  out4[(size_t)obin * 64 + lane] = m;
}

extern "C" void kernel_launch(void* const* d_in, const int* in_sizes, int n_in,
                              void* d_out, int out_size, void* d_ws, size_t ws_size,
                              hipStream_t stream) {
  const float4* fm4 = (const float4*)d_in[0];
  const float* rois = (const float*)d_in[1];
  float4* out4 = (float4*)d_out;
  roi_pool_kernel<<<NBINS, 64, 0, stream>>>(fm4, rois, out4);
}

// Round 10
// 11.115 us; speedup vs baseline: 5.6411x; 1.0662x over previous
//
#include <hip/hip_runtime.h>
#include <math.h>

// RoI pooling: fm [2,56,56,256] f32, rois [2,48,4] f32 (x, y_max, w, h),
// out [2,48,7,7,256] f32.
//
// Round 10: kill the straggler tail. Round-7 probe arithmetic showed dur is
// set by corner-bin waves doing up to 9 SERIAL chunk-waits (~900cy each
// cold); per-wave pipelining can't hide that (needs ~280 VGPRs of loads in
// flight). So: 4 WAVES PER BIN (256-thread block), round-robin row split
// (wave W takes rows W, W+4, W+8 -> R<=3 rows), exact unpadded loads, <=2
// vmcnt waits per wave, LDS max-combine, wave 0 writes. Loads forced via
// inline-asm (round-7: compiler otherwise serializes at low VGPR), one
// s_waitcnt vmcnt(0) + sched_barrier(0) per batch (rule #18).

#define NB 2
#define NR 48
#define FH 56
#define FW 56
#define PH 7
#define PW 7
#define NBINS (NB * NR * PH * PW)   // 4704 blocks = 8 XCD groups * 588

__device__ inline void fm4max(float4& m, const float4 v) {
  m.x = fmaxf(m.x, v.x);
  m.y = fmaxf(m.y, v.y);
  m.z = fmaxf(m.z, v.z);
  m.w = fmaxf(m.w, v.w);
}

__device__ inline float4 gload(const float4* p) {
  float4 v;
  asm volatile("global_load_dwordx4 %0, %1, off" : "=v"(v) : "v"(p));
  return v;
}

// Exact RxK pixel batch: rows row0 + 4k (k<R), cols c0..c0+K-1.
// All R*K loads issued back-to-back (<=15), ONE wait, fmax tree.
template <int R, int K>
__device__ inline float4 pool_part(const float4* __restrict__ base,
                                   int row0, int c0) {
  float4 v[R][K];
#pragma unroll
  for (int k = 0; k < R; ++k) {
    const float4* rowp =
        base + (size_t)(row0 + 4 * k) * (FW * 64) + (size_t)c0 * 64;
#pragma unroll
    for (int q = 0; q < K; ++q) v[k][q] = gload(rowp + (size_t)q * 64);
  }
  asm volatile("s_waitcnt vmcnt(0)" ::: "memory");
  __builtin_amdgcn_sched_barrier(0);
  float4 m0 = v[0][0], m1 = v[0][1];            // K >= 2 always
#pragma unroll
  for (int k = 0; k < R; ++k)
#pragma unroll
    for (int q = 0; q < K; ++q) {
      if (k == 0 && q < 2) continue;
      if (((k * K + q) & 1) == 0) fm4max(m0, v[k][q]);
      else                        fm4max(m1, v[k][q]);
    }
  fm4max(m0, m1);
  return m0;
}

// This wave's R rows x full bin width Ew (wave-uniform switch; Ew in [2,10]).
// Ew<=5: one batch/one wait. Ew>=6: two exact batches (no padding).
template <int R>
__device__ inline float4 pool_R(const float4* __restrict__ base,
                                int r0w, int c0, int Ew) {
  switch (Ew) {
    case 2: return pool_part<R, 2>(base, r0w, c0);
    case 3: return pool_part<R, 3>(base, r0w, c0);
    case 4: return pool_part<R, 4>(base, r0w, c0);
    case 5: return pool_part<R, 5>(base, r0w, c0);
    case 6: { float4 a = pool_part<R, 3>(base, r0w, c0);
              float4 b = pool_part<R, 3>(base, r0w, c0 + 3);
              fm4max(a, b); return a; }
    case 7: { float4 a = pool_part<R, 4>(base, r0w, c0);
              float4 b = pool_part<R, 3>(base, r0w, c0 + 4);
              fm4max(a, b); return a; }
    case 8: { float4 a = pool_part<R, 4>(base, r0w, c0);
              float4 b = pool_part<R, 4>(base, r0w, c0 + 4);
              fm4max(a, b); return a; }
    case 9: { float4 a = pool_part<R, 5>(base, r0w, c0);
              float4 b = pool_part<R, 4>(base, r0w, c0 + 5);
              fm4max(a, b); return a; }
    default:{ float4 a = pool_part<R, 5>(base, r0w, c0);
              float4 b = pool_part<R, 5>(base, r0w, c0 + 5);
              fm4max(a, b); return a; }
  }
}

__global__ __launch_bounds__(256) void roi_pool_kernel(
    const float4* __restrict__ fm4, const float* __restrict__ rois,
    float4* __restrict__ out4) {
  const int lane = threadIdx.x & 63;          // channel group (4 ch each)
  const int wv = threadIdx.x >> 6;            // 0..3: row-split wave id
  // XCD swizzle: round-robin p%8 -> XCD; contiguous 588-bin slab per XCD
  // (image b=0 on XCDs 0-3, b=1 on 4-7; per-XCD set 3.2 MB fits 4 MB L2).
  const int p = blockIdx.x;
  int bin = (p & 7) * (NBINS / 8) + (p >> 3);
  const int obin = bin;

  const int j = bin % PW; bin /= PW;
  const int i = bin % PH; bin /= PH;
  const int r = bin % NR;
  const int b = bin / NR;

  const float* roi = rois + (b * NR + r) * 4;
  const float x = roi[0], y = roi[1], w = roi[2], h = roi[3];

  // Match JAX reference fp32 arithmetic + trunc-to-int32 exactly.
  const int w_start = (int)(56.0f * x);
  const int w_end   = (int)(56.0f * (x + w));
  const int h_start = (int)(56.0f * (1.0f - y));
  const int h_end   = (int)(56.0f * (1.0f - y + h));
  const int rh = h_end - h_start;
  const int rw = w_end - w_start;
  const int h_step = rh / PH;
  const int w_step = rw / PW;

  const int r0 = h_start + i * h_step;
  const int r1 = (i == PH - 1) ? (h_start + rh) : (r0 + h_step);
  const int c0 = w_start + j * w_step;
  const int c1 = (j == PW - 1) ? (w_start + rw) : (c0 + w_step);

  const int Eh = r1 - r0;                     // in [2, 10]
  const int Ew = c1 - c0;                     // in [2, 10]

  // Round-robin rows: wave wv owns rows r0+wv, r0+wv+4, r0+wv+8 (< r1).
  const int R = (Eh - wv + 3) >> 2;           // 0..3 rows for this wave

  const float4* base = fm4 + ((size_t)(b * FH) * FW) * 64 + lane;

  float4 m = make_float4(-INFINITY, -INFINITY, -INFINITY, -INFINITY);
  if (R == 1)      m = pool_R<1>(base, r0 + wv, c0, Ew);
  else if (R == 2) m = pool_R<2>(base, r0 + wv, c0, Ew);
  else if (R == 3) m = pool_R<3>(base, r0 + wv, c0, Ew);

  __shared__ float4 red[4][64];
  red[wv][lane] = m;
  __syncthreads();
  if (wv == 0) {
    fm4max(m, red[1][lane]);
    fm4max(m, red[2][lane]);
    fm4max(m, red[3][lane]);
    out4[(size_t)obin * 64 + lane] = m;
  }
}

extern "C" void kernel_launch(void* const* d_in, const int* in_sizes, int n_in,
                              void* d_out, int out_size, void* d_ws, size_t ws_size,
                              hipStream_t stream) {
  const float4* fm4 = (const float4*)d_in[0];
  const float* rois = (const float*)d_in[1];
  float4* out4 = (float4*)d_out;
  roi_pool_kernel<<<NBINS, 256, 0, stream>>>(fm4, rois, out4);
}